// Round 1
// baseline (376.652 us; speedup 1.0000x reference)
//
#include <hip/hip_runtime.h>
#include <cmath>

#define EPSF 1e-5f

// ---------------------------------------------------------------------------
// ws float layout (tables only):
//   W2F   = ws        : float4[15][7][45]  folded stage-2 conv weights (expert innermost)
//   B2F   = +18900    : float [15][45]     folded stage-2 bias (675, +1 pad)
//   FC2   = +19576    : float4[2][15][45]  fcw2 re-laid (expert innermost)
//   FCB2  = +24976    : float [2][45]      (90, +2 pad)
//   W1P   = +25068    : float [20][12]     folded stage-1 conv weights, row pad 9->12
//   FCW1R = +25308    : float [20][9][12]  fcw1 re-laid [ch][pp][class pad 10->12]
//   B1F   = +27468    : float [20]
// total 27488 floats (~110 KB)
// ---------------------------------------------------------------------------
#define OFF_B2F   18900
#define OFF_FC2   19576
#define OFF_FCB2  24976
#define OFF_W1P   25068
#define OFF_FCW1R 25308
#define OFF_B1F   27468

__global__ __launch_bounds__(256) void setup_tables(
    const float* __restrict__ w1, const float* __restrict__ b1,
    const float* __restrict__ g1, const float* __restrict__ be1,
    const float* __restrict__ m1, const float* __restrict__ v1,
    const float* __restrict__ w2, const float* __restrict__ b2,
    const float* __restrict__ g2, const float* __restrict__ be2,
    const float* __restrict__ m2, const float* __restrict__ v2,
    const float* __restrict__ fcw2, const float* __restrict__ fcb2,
    const float* __restrict__ fcw1,
    float* __restrict__ ws)
{
  const int t  = blockIdx.x * blockDim.x + threadIdx.x;
  const int nt = gridDim.x * blockDim.x;
  float* W2F   = ws;
  float* B2F   = ws + OFF_B2F;
  float* FC2   = ws + OFF_FC2;
  float* FCB2  = ws + OFF_FCB2;
  float* W1P   = ws + OFF_W1P;
  float* FCW1R = ws + OFF_FCW1R;
  float* B1F   = ws + OFF_B1F;

  for (int idx = t; idx < 18900; idx += nt) {
    int kk = idx & 3, rest = idx >> 2;
    int e = rest % 45, ok4 = rest / 45;
    int k4 = ok4 % 7, o = ok4 / 7;
    int k = k4 * 4 + kk;
    float s = g2[e*15+o] / sqrtf(v2[e*15+o] + EPSF);
    W2F[idx] = (k < 25) ? w2[(e*15+o)*25 + k] * s : 0.0f;
  }
  for (int idx = t; idx < 675; idx += nt) {
    int e = idx % 45, o = idx / 45;
    float s = g2[e*15+o] / sqrtf(v2[e*15+o] + EPSF);
    B2F[idx] = b2[e*15+o]*s + be2[e*15+o] - m2[e*15+o]*s;
  }
  for (int idx = t; idx < 5400; idx += nt) {
    int kk = idx & 3, rest = idx >> 2;
    int e = rest % 45, t2 = rest / 45;
    int f4 = t2 % 15, oo = t2 / 15;
    FC2[idx] = fcw2[(e*2+oo)*60 + f4*4 + kk];
  }
  for (int idx = t; idx < 90; idx += nt) {
    int e = idx % 45, oo = idx / 45;
    FCB2[idx] = fcb2[e*2+oo];
  }
  for (int idx = t; idx < 240; idx += nt) {
    int j = idx % 12, ch = idx / 12;
    float s = g1[ch] / sqrtf(v1[ch] + EPSF);
    W1P[idx] = (j < 9) ? w1[ch*9 + j] * s : 0.0f;
  }
  for (int idx = t; idx < 2160; idx += nt) {
    int c = idx % 12, r2 = idx / 12;
    int pp = r2 % 9, ch = r2 / 9;
    FCW1R[idx] = (c < 10) ? fcw1[c*180 + ch*9 + pp] : 0.0f;
  }
  for (int idx = t; idx < 20; idx += nt) {
    float s = g1[idx] / sqrtf(v1[idx] + EPSF);
    B1F[idx] = b1[idx]*s + be1[idx] - m1[idx]*s;
  }
}

// component access into float4 array with compile-time index (after unroll)
#define GETC(arr, k) ((k)%4==0 ? arr[(k)/4].x : (k)%4==1 ? arr[(k)/4].y : \
                      (k)%4==2 ? arr[(k)/4].z : arr[(k)/4].w)

// ---------------------------------------------------------------------------
// Fused kernel, 4 threads per sample (lane = 4*s + part).
//   - cooperative downscale (part p -> out rows 2p,2p+1) shared via LDS
//   - stage-1 channels split 5/part, stage-2 channels split o = p+4*oi
//   - shfl_xor(1)/(2) butterfly all-reduces (bit-identical on all 4 lanes)
//   - xd row 8 / col 8 are provably unused by both stages -> xd is 8x8 (64 regs),
//     raw rows 24..26 and the last float4 of each row are never loaded.
// Block 256 thr = 4 waves = 64 samples; grid 1024 blocks -> 4096 waves;
// __launch_bounds__(256,3): 3 blocks/CU = 12 waves/CU (vs 4 before).
// ---------------------------------------------------------------------------
__global__ __launch_bounds__(256, 3) void fused_k(
    const float* __restrict__ x,
    const float* __restrict__ ws,
    const float* __restrict__ fcb1,
    float* __restrict__ out, int B)
{
  // sample stride 68 floats (272B): 16B-aligned, 4*sl%32 spreads banks (<=2-way)
  __shared__ float xds[64 * 68];   // 17.4 KB

  const int t  = threadIdx.x;
  const int p  = t & 3;            // part 0..3
  const int sl = t >> 2;           // sample slot in block 0..63
  const int b  = blockIdx.x * 64 + sl;
  const bool valid = (b < B);

  const float* W2F   = ws;
  const float* B2F   = ws + OFF_B2F;
  const float* FC2   = ws + OFF_FC2;
  const float* FCB2  = ws + OFF_FCB2;
  const float* W1P   = ws + OFF_W1P;
  const float* FCW1R = ws + OFF_FCW1R;
  const float* B1F   = ws + OFF_B1F;

  // ---- cooperative downscale 28x28 -> 8x8 (rows/cols 0..7 only) ----
  if (valid) {
    const float* xb = x + (size_t)b * 784;
    #pragma unroll
    for (int ri = 0; ri < 2; ri++) {
      const int r = 2*p + ri;
      float4 rowv[3][6];
      #pragma unroll
      for (int dr = 0; dr < 3; dr++) {
        const float4* rv = reinterpret_cast<const float4*>(xb + (3*r + dr) * 28);
        #pragma unroll
        for (int q = 0; q < 6; q++) rowv[dr][q] = rv[q];
      }
      float d[8];
      #pragma unroll
      for (int c = 0; c < 8; c++) {
        float s = 0.0f;
        #pragma unroll
        for (int dr = 0; dr < 3; dr++)
          s += GETC(rowv[dr], 3*c) + GETC(rowv[dr], 3*c+1) + GETC(rowv[dr], 3*c+2);
        d[c] = s * (1.0f / 9.0f);
      }
      float4* dst = reinterpret_cast<float4*>(&xds[sl*68 + r*8]);
      dst[0] = make_float4(d[0], d[1], d[2], d[3]);
      dst[1] = make_float4(d[4], d[5], d[6], d[7]);
    }
  }
  __syncthreads();

  // every part reads its sample's full 8x8 tile back into registers
  float xd[64];
  #pragma unroll
  for (int r = 0; r < 8; r++) {
    const float4* src = reinterpret_cast<const float4*>(&xds[sl*68 + r*8]);
    float4 a = src[0], bq = src[1];
    xd[r*8+0]=a.x;  xd[r*8+1]=a.y;  xd[r*8+2]=a.z;  xd[r*8+3]=a.w;
    xd[r*8+4]=bq.x; xd[r*8+5]=bq.y; xd[r*8+6]=bq.z; xd[r*8+7]=bq.w;
  }

  // ---- stage 1: 5 channels per part -> partial logits ----
  float logits[10];
  #pragma unroll
  for (int c = 0; c < 10; c++) logits[c] = 0.0f;

  #pragma unroll 1
  for (int ci = 0; ci < 5; ci++) {
    const int ch = p*5 + ci;
    const float4* wp = reinterpret_cast<const float4*>(W1P + ch*12);
    float4 w0 = wp[0], w1v = wp[1], w2v = wp[2];
    const float w_[9] = {w0.x,w0.y,w0.z,w0.w,w1v.x,w1v.y,w1v.z,w1v.w,w2v.x};
    const float bb = B1F[ch];
    float feat[9];
    #pragma unroll
    for (int pr = 0; pr < 3; pr++) {
      #pragma unroll
      for (int pc = 0; pc < 3; pc++) {
        float c00 = bb, c01 = bb, c10 = bb, c11 = bb;
        #pragma unroll
        for (int dr = 0; dr < 3; dr++) {
          #pragma unroll
          for (int dc = 0; dc < 3; dc++) {
            float wk = w_[dr*3 + dc];
            c00 = fmaf(xd[(2*pr+0+dr)*8 + 2*pc+0+dc], wk, c00);
            c01 = fmaf(xd[(2*pr+0+dr)*8 + 2*pc+1+dc], wk, c01);
            c10 = fmaf(xd[(2*pr+1+dr)*8 + 2*pc+0+dc], wk, c10);
            c11 = fmaf(xd[(2*pr+1+dr)*8 + 2*pc+1+dc], wk, c11);
          }
        }
        feat[pr*3+pc] = fmaxf(fmaxf(fmaxf(c00, c01), fmaxf(c10, c11)), 0.0f);
      }
    }
    #pragma unroll
    for (int pp = 0; pp < 9; pp++) {
      const float4* f4 = reinterpret_cast<const float4*>(FCW1R + (ch*9 + pp)*12);
      float4 f0 = f4[0], f1 = f4[1], f2 = f4[2];
      const float fv = feat[pp];
      logits[0] = fmaf(fv, f0.x, logits[0]);
      logits[1] = fmaf(fv, f0.y, logits[1]);
      logits[2] = fmaf(fv, f0.z, logits[2]);
      logits[3] = fmaf(fv, f0.w, logits[3]);
      logits[4] = fmaf(fv, f1.x, logits[4]);
      logits[5] = fmaf(fv, f1.y, logits[5]);
      logits[6] = fmaf(fv, f1.z, logits[6]);
      logits[7] = fmaf(fv, f1.w, logits[7]);
      logits[8] = fmaf(fv, f2.x, logits[8]);
      logits[9] = fmaf(fv, f2.y, logits[9]);
    }
  }

  // butterfly all-reduce over the 4 parts (bit-identical on all lanes), + bias
  #pragma unroll
  for (int c = 0; c < 10; c++) {
    float v = logits[c];
    v += __shfl_xor(v, 1);
    v += __shfl_xor(v, 2);
    logits[c] = v + fcb1[c];
  }

  // ---- top-2 (stable-argsort tie semantics: later index wins on tie) ----
  int i1 = 0; float v1m = logits[0];
  #pragma unroll
  for (int c = 1; c < 10; c++) { if (logits[c] >= v1m) { v1m = logits[c]; i1 = c; } }
  int i2 = 0; float v2m = -3.0e38f;
  #pragma unroll
  for (int c = 0; c < 10; c++) { if (c != i1 && logits[c] >= v2m) { v2m = logits[c]; i2 = c; } }
  const int idx0 = i1 < i2 ? i1 : i2;
  const int idx1 = i1 < i2 ? i2 : i1;
  int eid = 8*idx0 - (idx0*(idx0-1))/2 + idx1 - 1;   // PAIR_TABLE[idx0][idx1]
  eid = eid < 0 ? 0 : (eid > 44 ? 44 : eid);          // guards garbage lanes (b>=B)

  float sume = 0.0f;
  #pragma unroll
  for (int c = 0; c < 10; c++) sume += expf(logits[c] - v1m);
  const bool use1 = (-logf(sume)) > 0.3f;

  // ---- stage 2: channels o = p + 4*oi (part 3 gets 3 channels) ----
  const float4* W2F4 = reinterpret_cast<const float4*>(W2F);
  const float4* FC24 = reinterpret_cast<const float4*>(FC2);
  float s2a = 0.0f, s2b = 0.0f;

  #pragma unroll 1
  for (int oi = 0; oi < 4; oi++) {
    const int o = p + 4*oi;
    if (o < 15) {
      float4 wv[7];
      #pragma unroll
      for (int k4 = 0; k4 < 7; k4++) wv[k4] = W2F4[(o*7 + k4)*45 + eid];
      const float bias = B2F[o*45 + eid];
      const float4 fa = FC24[o*45 + eid];
      const float4 fb = FC24[(15 + o)*45 + eid];
      float feat0 = 0.f, feat1 = 0.f, feat2 = 0.f, feat3 = 0.f;
      #pragma unroll
      for (int ph = 0; ph < 2; ph++) {
        #pragma unroll
        for (int pw = 0; pw < 2; pw++) {
          float c00 = bias, c01 = bias, c10 = bias, c11 = bias;
          #pragma unroll
          for (int i = 0; i < 5; i++) {
            #pragma unroll
            for (int j = 0; j < 5; j++) {
              float wk = GETC(wv, i*5 + j);
              c00 = fmaf(xd[(2*ph+0+i)*8 + 2*pw+0+j], wk, c00);
              c01 = fmaf(xd[(2*ph+0+i)*8 + 2*pw+1+j], wk, c01);
              c10 = fmaf(xd[(2*ph+1+i)*8 + 2*pw+0+j], wk, c10);
              c11 = fmaf(xd[(2*ph+1+i)*8 + 2*pw+1+j], wk, c11);
            }
          }
          float f = fmaxf(fmaxf(fmaxf(c00, c01), fmaxf(c10, c11)), 0.0f);
          if (ph == 0 && pw == 0) feat0 = f;
          else if (ph == 0)       feat1 = f;
          else if (pw == 0)       feat2 = f;
          else                    feat3 = f;
        }
      }
      s2a = fmaf(feat0, fa.x, fmaf(feat1, fa.y, fmaf(feat2, fa.z, fmaf(feat3, fa.w, s2a))));
      s2b = fmaf(feat0, fb.x, fmaf(feat1, fb.y, fmaf(feat2, fb.z, fmaf(feat3, fb.w, s2b))));
    }
  }
  s2a += __shfl_xor(s2a, 1); s2a += __shfl_xor(s2a, 2);
  s2b += __shfl_xor(s2b, 1); s2b += __shfl_xor(s2b, 2);
  s2a += FCB2[eid];
  s2b += FCB2[45 + eid];

  // ---- scatter + log_softmax; parts 0/1 write logits, parts 2/3 write out2 ----
  float o10[10];
  #pragma unroll
  for (int c = 0; c < 10; c++) {
    float v = -100.0f;
    v = (c == idx0) ? s2a : v;
    v = (c == idx1) ? s2b : v;
    o10[c] = use1 ? logits[c] : v;
  }
  float m2x = o10[0];
  #pragma unroll
  for (int c = 1; c < 10; c++) m2x = fmaxf(m2x, o10[c]);
  float se2 = 0.0f;
  #pragma unroll
  for (int c = 0; c < 10; c++) se2 += expf(o10[c] - m2x);
  const float lse2 = m2x + logf(se2);

  if (valid) {
    const size_t base = (size_t)b * 10;
    if (p == 0) {
      #pragma unroll
      for (int c = 0; c < 5; c++) out[base + c] = logits[c];
    } else if (p == 1) {
      #pragma unroll
      for (int c = 5; c < 10; c++) out[base + c] = logits[c];
    } else if (p == 2) {
      #pragma unroll
      for (int c = 0; c < 5; c++) out[(size_t)B*10 + base + c] = o10[c] - lse2;
    } else {
      #pragma unroll
      for (int c = 5; c < 10; c++) out[(size_t)B*10 + base + c] = o10[c] - lse2;
    }
  }
}

extern "C" void kernel_launch(void* const* d_in, const int* in_sizes, int n_in,
                              void* d_out, int out_size, void* d_ws, size_t ws_size,
                              hipStream_t stream) {
  const float* x    = (const float*)d_in[0];
  const float* w1   = (const float*)d_in[1];
  const float* b1   = (const float*)d_in[2];
  const float* g1   = (const float*)d_in[3];
  const float* be1  = (const float*)d_in[4];
  const float* m1   = (const float*)d_in[5];
  const float* v1   = (const float*)d_in[6];
  const float* fcw1 = (const float*)d_in[7];
  const float* fcb1 = (const float*)d_in[8];
  const float* w2   = (const float*)d_in[9];
  const float* b2   = (const float*)d_in[10];
  const float* g2   = (const float*)d_in[11];
  const float* be2  = (const float*)d_in[12];
  const float* m2   = (const float*)d_in[13];
  const float* v2   = (const float*)d_in[14];
  const float* fcw2 = (const float*)d_in[15];
  const float* fcb2 = (const float*)d_in[16];
  float* out = (float*)d_out;
  float* ws  = (float*)d_ws;
  const int B = in_sizes[0] / 784;

  setup_tables<<<80, 256, 0, stream>>>(w1, b1, g1, be1, m1, v1,
                                       w2, b2, g2, be2, m2, v2, fcw2, fcb2, fcw1, ws);
  fused_k<<<(B + 63)/64, 256, 0, stream>>>(x, ws, fcb1, out, B);
}

// Round 2
// 334.383 us; speedup vs baseline: 1.1264x; 1.1264x over previous
//
#include <hip/hip_runtime.h>
#include <cmath>

#define EPSF 1e-5f

// ---------------------------------------------------------------------------
// ws float layout:
//   W2F  = ws        : float4[15][7][45]  folded stage-2 conv weights (expert innermost)
//   FC2  = +19576    : float4[2][15][45]  fcw2 re-laid (expert innermost)
//   IMG  = +25088    : float [4096]       LDS image (stage-1 tables + s2 bias tables):
//       [0,240)    W1P   [20][12] folded stage-1 conv w (row pad 9->12)
//       [240,2400) FCW1R [20][9][12] fcw1 re-laid [ch][pp][class pad 10->12]
//       [2400,2420) B1F  [20] folded stage-1 bias
//       [2420,2432) FCB1 [10] (+2 pad)
//       [2432,3108) B2F  [15][45] folded stage-2 bias (+1 pad)
//       [3108,4096) FCB2 [2][45] (+pad)
// total 29184 floats (~117 KB)
// ---------------------------------------------------------------------------
#define OFF_FC2   19576
#define OFF_IMG   25088

// image-relative offsets (also the LDS offsets relative to T_TAB)
#define I_W1P    0
#define I_FCW1R  240
#define I_B1F    2400
#define I_FCB1   2420
#define I_B2F    2432
#define I_FCB2   3108

__global__ __launch_bounds__(256) void setup_tables(
    const float* __restrict__ w1, const float* __restrict__ b1,
    const float* __restrict__ g1, const float* __restrict__ be1,
    const float* __restrict__ m1, const float* __restrict__ v1,
    const float* __restrict__ w2, const float* __restrict__ b2,
    const float* __restrict__ g2, const float* __restrict__ be2,
    const float* __restrict__ m2, const float* __restrict__ v2,
    const float* __restrict__ fcw2, const float* __restrict__ fcb2,
    const float* __restrict__ fcw1, const float* __restrict__ fcb1,
    float* __restrict__ ws)
{
  const int t  = blockIdx.x * blockDim.x + threadIdx.x;
  const int nt = gridDim.x * blockDim.x;
  float* W2F = ws;
  float* FC2 = ws + OFF_FC2;
  float* IMG = ws + OFF_IMG;

  for (int idx = t; idx < 18900; idx += nt) {
    int kk = idx & 3, rest = idx >> 2;
    int e = rest % 45, ok4 = rest / 45;
    int k4 = ok4 % 7, o = ok4 / 7;
    int k = k4 * 4 + kk;
    float s = g2[e*15+o] / sqrtf(v2[e*15+o] + EPSF);
    W2F[idx] = (k < 25) ? w2[(e*15+o)*25 + k] * s : 0.0f;
  }
  for (int idx = t; idx < 5400; idx += nt) {
    int kk = idx & 3, rest = idx >> 2;
    int e = rest % 45, t2 = rest / 45;
    int f4 = t2 % 15, oo = t2 / 15;
    FC2[idx] = fcw2[(e*2+oo)*60 + f4*4 + kk];
  }
  for (int i = t; i < 4096; i += nt) {
    float v = 0.0f;
    if (i < I_FCW1R) {                       // W1P
      int ch = i / 12, j = i % 12;
      if (j < 9) {
        float s = g1[ch] / sqrtf(v1[ch] + EPSF);
        v = w1[ch*9 + j] * s;
      }
    } else if (i < I_B1F) {                  // FCW1R
      int k = i - I_FCW1R;
      int c = k % 12, r2 = k / 12, pp = r2 % 9, ch = r2 / 9;
      if (c < 10) v = fcw1[c*180 + ch*9 + pp];
    } else if (i < I_FCB1) {                 // B1F
      int ch = i - I_B1F;
      float s = g1[ch] / sqrtf(v1[ch] + EPSF);
      v = b1[ch]*s + be1[ch] - m1[ch]*s;
    } else if (i < I_B2F) {                  // FCB1
      int k = i - I_FCB1;
      if (k < 10) v = fcb1[k];
    } else if (i < I_FCB2) {                 // B2F
      int k = i - I_B2F;
      if (k < 675) {
        int e = k % 45, o = k / 45;
        float s = g2[e*15+o] / sqrtf(v2[e*15+o] + EPSF);
        v = b2[e*15+o]*s + be2[e*15+o] - m2[e*15+o]*s;
      }
    } else {                                 // FCB2
      int k = i - I_FCB2;
      if (k < 90) {
        int e = k % 45, oo = k / 45;
        v = fcb2[e*2+oo];
      }
    }
    IMG[i] = v;
  }
}

// component access into float4 array with compile-time index (after unroll)
#define GETC(arr, k) ((k)%4==0 ? arr[(k)/4].x : (k)%4==1 ? arr[(k)/4].y : \
                      (k)%4==2 ? arr[(k)/4].z : arr[(k)/4].w)

// ---------------------------------------------------------------------------
// 4 threads per sample.  LDS layout (floats):
//   [0,4352)      xds: 64 samples x 68-float stride (8x8 tile at sl*68)
//                 -- reused after stage 1: [0,640) out1 staging (= logits),
//                                          [640,1280) out2 staging
//   [4352,8448)   TAB: copy of ws IMG (stage-1 weights + s2 bias tables)
// amdgpu_waves_per_eu(2,4): cap occupancy target at 4 waves/EU (grid limit)
// so the allocator gets a 128-VGPR budget and does NOT spill xd[64] (round-1
// post-mortem: 84 VGPR + ~14 MB scratch round-trip = the 103 us stall).
// ---------------------------------------------------------------------------
#define T_TAB 4352

__global__ __attribute__((amdgpu_waves_per_eu(2, 4))) __launch_bounds__(256)
void fused_k(
    const float* __restrict__ x,
    const float* __restrict__ ws,
    float* __restrict__ out, int B)
{
  __shared__ float lds[8448];   // 33 KB -> 4 blocks/CU fits

  const int t  = threadIdx.x;
  const int p  = t & 3;            // part 0..3
  const int sl = t >> 2;           // sample slot in block 0..63
  const int b  = blockIdx.x * 64 + sl;
  const bool valid = (b < B);

  // ---- issue TAB copy loads first (L2/small), then x loads (HBM/long) ----
  const float4* img4 = reinterpret_cast<const float4*>(ws + OFF_IMG);
  float4 tv0 = img4[t], tv1 = img4[t + 256], tv2 = img4[t + 512], tv3 = img4[t + 768];

  // ---- cooperative downscale 28x28 -> 8x8 (rows/cols 0..7 only) ----
  if (valid) {
    const float* xb = x + (size_t)b * 784;
    #pragma unroll
    for (int ri = 0; ri < 2; ri++) {
      const int r = 2*p + ri;
      float4 rowv[3][6];
      #pragma unroll
      for (int dr = 0; dr < 3; dr++) {
        const float4* rv = reinterpret_cast<const float4*>(xb + (3*r + dr) * 28);
        #pragma unroll
        for (int q = 0; q < 6; q++) rowv[dr][q] = rv[q];
      }
      float d[8];
      #pragma unroll
      for (int c = 0; c < 8; c++) {
        float s = 0.0f;
        #pragma unroll
        for (int dr = 0; dr < 3; dr++)
          s += GETC(rowv[dr], 3*c) + GETC(rowv[dr], 3*c+1) + GETC(rowv[dr], 3*c+2);
        d[c] = s * (1.0f / 9.0f);
      }
      float4* dst = reinterpret_cast<float4*>(&lds[sl*68 + r*8]);
      dst[0] = make_float4(d[0], d[1], d[2], d[3]);
      dst[1] = make_float4(d[4], d[5], d[6], d[7]);
    }
  }
  // write TAB to LDS (waits only on the img loads, issued before x loads)
  {
    float4* tab4 = reinterpret_cast<float4*>(&lds[T_TAB]);
    tab4[t] = tv0; tab4[t + 256] = tv1; tab4[t + 512] = tv2; tab4[t + 768] = tv3;
  }
  __syncthreads();

  // every part reads its sample's full 8x8 tile back into registers
  float xd[64];
  #pragma unroll
  for (int r = 0; r < 8; r++) {
    const float4* src = reinterpret_cast<const float4*>(&lds[sl*68 + r*8]);
    float4 a = src[0], bq = src[1];
    xd[r*8+0]=a.x;  xd[r*8+1]=a.y;  xd[r*8+2]=a.z;  xd[r*8+3]=a.w;
    xd[r*8+4]=bq.x; xd[r*8+5]=bq.y; xd[r*8+6]=bq.z; xd[r*8+7]=bq.w;
  }

  // ---- stage 1: 5 channels per part (weights from LDS) ----
  float logits[10];
  #pragma unroll
  for (int c = 0; c < 10; c++) logits[c] = 0.0f;

  #pragma unroll 1
  for (int ci = 0; ci < 5; ci++) {
    const int ch = p*5 + ci;
    const float4* wp = reinterpret_cast<const float4*>(&lds[T_TAB + I_W1P + ch*12]);
    float4 w0 = wp[0], w1v = wp[1], w2v = wp[2];
    const float w_[9] = {w0.x,w0.y,w0.z,w0.w,w1v.x,w1v.y,w1v.z,w1v.w,w2v.x};
    const float bb = lds[T_TAB + I_B1F + ch];
    float feat[9];
    #pragma unroll
    for (int pr = 0; pr < 3; pr++) {
      #pragma unroll
      for (int pc = 0; pc < 3; pc++) {
        float c00 = bb, c01 = bb, c10 = bb, c11 = bb;
        #pragma unroll
        for (int dr = 0; dr < 3; dr++) {
          #pragma unroll
          for (int dc = 0; dc < 3; dc++) {
            float wk = w_[dr*3 + dc];
            c00 = fmaf(xd[(2*pr+0+dr)*8 + 2*pc+0+dc], wk, c00);
            c01 = fmaf(xd[(2*pr+0+dr)*8 + 2*pc+1+dc], wk, c01);
            c10 = fmaf(xd[(2*pr+1+dr)*8 + 2*pc+0+dc], wk, c10);
            c11 = fmaf(xd[(2*pr+1+dr)*8 + 2*pc+1+dc], wk, c11);
          }
        }
        feat[pr*3+pc] = fmaxf(fmaxf(fmaxf(c00, c01), fmaxf(c10, c11)), 0.0f);
      }
    }
    #pragma unroll
    for (int pp = 0; pp < 9; pp++) {
      const float4* f4 = reinterpret_cast<const float4*>(&lds[T_TAB + I_FCW1R + (ch*9 + pp)*12]);
      float4 f0 = f4[0], f1 = f4[1], f2 = f4[2];
      const float fv = feat[pp];
      logits[0] = fmaf(fv, f0.x, logits[0]);
      logits[1] = fmaf(fv, f0.y, logits[1]);
      logits[2] = fmaf(fv, f0.z, logits[2]);
      logits[3] = fmaf(fv, f0.w, logits[3]);
      logits[4] = fmaf(fv, f1.x, logits[4]);
      logits[5] = fmaf(fv, f1.y, logits[5]);
      logits[6] = fmaf(fv, f1.z, logits[6]);
      logits[7] = fmaf(fv, f1.w, logits[7]);
      logits[8] = fmaf(fv, f2.x, logits[8]);
      logits[9] = fmaf(fv, f2.y, logits[9]);
    }
  }

  // butterfly all-reduce over the 4 parts (bit-identical on all lanes), + bias
  #pragma unroll
  for (int c = 0; c < 10; c++) {
    float v = logits[c];
    v += __shfl_xor(v, 1);
    v += __shfl_xor(v, 2);
    logits[c] = v + lds[T_TAB + I_FCB1 + c];
  }

  // ---- top-2 (stable-argsort tie semantics: later index wins on tie) ----
  int i1 = 0; float v1m = logits[0];
  #pragma unroll
  for (int c = 1; c < 10; c++) { if (logits[c] >= v1m) { v1m = logits[c]; i1 = c; } }
  int i2 = 0; float v2m = -3.0e38f;
  #pragma unroll
  for (int c = 0; c < 10; c++) { if (c != i1 && logits[c] >= v2m) { v2m = logits[c]; i2 = c; } }
  const int idx0 = i1 < i2 ? i1 : i2;
  const int idx1 = i1 < i2 ? i2 : i1;
  int eid = 8*idx0 - (idx0*(idx0-1))/2 + idx1 - 1;   // PAIR_TABLE[idx0][idx1]
  eid = eid < 0 ? 0 : (eid > 44 ? 44 : eid);          // guards garbage lanes

  float sume = 0.0f;
  #pragma unroll
  for (int c = 0; c < 10; c++) sume += __expf(logits[c] - v1m);
  const bool use1 = (-__logf(sume)) > 0.3f;

  // ---- stash logits (= out1) in LDS; frees 10 VGPRs across stage 2 ----
  __syncthreads();                       // all waves done reading xds region
  if (p == 0) {
    #pragma unroll
    for (int c = 0; c < 5; c++) lds[sl*10 + c] = logits[c];
  } else if (p == 1) {
    #pragma unroll
    for (int c = 5; c < 10; c++) lds[sl*10 + c] = logits[c];
  }

  // ---- stage 2: channels o = p + 4*oi (part 3 gets 3) ----
  const float4* W2F4 = reinterpret_cast<const float4*>(ws);
  const float4* FC24 = reinterpret_cast<const float4*>(ws + OFF_FC2);
  float s2a = 0.0f, s2b = 0.0f;

  #pragma unroll 1
  for (int oi = 0; oi < 4; oi++) {
    const int o = p + 4*oi;
    if (o < 15) {
      float4 wv[7];
      #pragma unroll
      for (int k4 = 0; k4 < 7; k4++) wv[k4] = W2F4[(o*7 + k4)*45 + eid];
      const float bias = lds[T_TAB + I_B2F + o*45 + eid];
      const float4 fa = FC24[o*45 + eid];
      const float4 fb = FC24[(15 + o)*45 + eid];
      float feat0 = 0.f, feat1 = 0.f, feat2 = 0.f, feat3 = 0.f;
      #pragma unroll
      for (int ph = 0; ph < 2; ph++) {
        #pragma unroll
        for (int pw = 0; pw < 2; pw++) {
          float c00 = bias, c01 = bias, c10 = bias, c11 = bias;
          #pragma unroll
          for (int i = 0; i < 5; i++) {
            #pragma unroll
            for (int j = 0; j < 5; j++) {
              float wk = GETC(wv, i*5 + j);
              c00 = fmaf(xd[(2*ph+0+i)*8 + 2*pw+0+j], wk, c00);
              c01 = fmaf(xd[(2*ph+0+i)*8 + 2*pw+1+j], wk, c01);
              c10 = fmaf(xd[(2*ph+1+i)*8 + 2*pw+0+j], wk, c10);
              c11 = fmaf(xd[(2*ph+1+i)*8 + 2*pw+1+j], wk, c11);
            }
          }
          float f = fmaxf(fmaxf(fmaxf(c00, c01), fmaxf(c10, c11)), 0.0f);
          if (ph == 0 && pw == 0) feat0 = f;
          else if (ph == 0)       feat1 = f;
          else if (pw == 0)       feat2 = f;
          else                    feat3 = f;
        }
      }
      s2a = fmaf(feat0, fa.x, fmaf(feat1, fa.y, fmaf(feat2, fa.z, fmaf(feat3, fa.w, s2a))));
      s2b = fmaf(feat0, fb.x, fmaf(feat1, fb.y, fmaf(feat2, fb.z, fmaf(feat3, fb.w, s2b))));
    }
  }
  s2a += __shfl_xor(s2a, 1); s2a += __shfl_xor(s2a, 2);
  s2b += __shfl_xor(s2b, 1); s2b += __shfl_xor(s2b, 2);
  s2a += lds[T_TAB + I_FCB2 + eid];
  s2b += lds[T_TAB + I_FCB2 + 45 + eid];

  // ---- scatter + log_softmax (logits read back from LDS) ----
  __syncthreads();                       // logits writes visible; safe ordering
  float o10[10];
  #pragma unroll
  for (int c = 0; c < 10; c++) {
    float v = -100.0f;
    v = (c == idx0) ? s2a : v;
    v = (c == idx1) ? s2b : v;
    o10[c] = use1 ? lds[sl*10 + c] : v;
  }
  float m2x = o10[0];
  #pragma unroll
  for (int c = 1; c < 10; c++) m2x = fmaxf(m2x, o10[c]);
  float se2 = 0.0f;
  #pragma unroll
  for (int c = 0; c < 10; c++) se2 += __expf(o10[c] - m2x);
  const float lse2 = m2x + __logf(se2);

  // ---- stage out2 into LDS; coalesced float4 block store ----
  if (p == 2) {
    #pragma unroll
    for (int c = 0; c < 5; c++) lds[640 + sl*10 + c] = o10[c] - lse2;
  } else if (p == 3) {
    #pragma unroll
    for (int c = 5; c < 10; c++) lds[640 + sl*10 + c] = o10[c] - lse2;
  }
  __syncthreads();

  if (blockIdx.x * 64 + 64 <= B) {       // full block: coalesced path
    const float4* l4 = reinterpret_cast<const float4*>(lds);
    const size_t o1 = (size_t)blockIdx.x * 640;
    if (t < 160)
      *reinterpret_cast<float4*>(out + o1 + (size_t)t*4) = l4[t];
    if (t >= 96)
      *reinterpret_cast<float4*>(out + (size_t)B*10 + o1 + (size_t)(t-96)*4) = l4[160 + (t-96)];
  } else if (valid) {                    // tail block fallback
    const size_t base = (size_t)b * 10;
    if (p == 0) {
      #pragma unroll
      for (int c = 0; c < 5; c++) out[base + c] = lds[sl*10 + c];
    } else if (p == 1) {
      #pragma unroll
      for (int c = 5; c < 10; c++) out[base + c] = lds[sl*10 + c];
    } else if (p == 2) {
      #pragma unroll
      for (int c = 0; c < 5; c++) out[(size_t)B*10 + base + c] = lds[640 + sl*10 + c];
    } else {
      #pragma unroll
      for (int c = 5; c < 10; c++) out[(size_t)B*10 + base + c] = lds[640 + sl*10 + c];
    }
  }
}

extern "C" void kernel_launch(void* const* d_in, const int* in_sizes, int n_in,
                              void* d_out, int out_size, void* d_ws, size_t ws_size,
                              hipStream_t stream) {
  const float* x    = (const float*)d_in[0];
  const float* w1   = (const float*)d_in[1];
  const float* b1   = (const float*)d_in[2];
  const float* g1   = (const float*)d_in[3];
  const float* be1  = (const float*)d_in[4];
  const float* m1   = (const float*)d_in[5];
  const float* v1   = (const float*)d_in[6];
  const float* fcw1 = (const float*)d_in[7];
  const float* fcb1 = (const float*)d_in[8];
  const float* w2   = (const float*)d_in[9];
  const float* b2   = (const float*)d_in[10];
  const float* g2   = (const float*)d_in[11];
  const float* be2  = (const float*)d_in[12];
  const float* m2   = (const float*)d_in[13];
  const float* v2   = (const float*)d_in[14];
  const float* fcw2 = (const float*)d_in[15];
  const float* fcb2 = (const float*)d_in[16];
  float* out = (float*)d_out;
  float* ws  = (float*)d_ws;
  const int B = in_sizes[0] / 784;

  setup_tables<<<80, 256, 0, stream>>>(w1, b1, g1, be1, m1, v1,
                                       w2, b2, g2, be2, m2, v2,
                                       fcw2, fcb2, fcw1, fcb1, ws);
  fused_k<<<(B + 63)/64, 256, 0, stream>>>(x, ws, out, B);
}